// Round 1
// baseline (1274.887 us; speedup 1.0000x reference)
//
#include <hip/hip_runtime.h>
#include <math.h>

#define EMB 1024
#define FF  4096
#define NE  8
#define TTOK 8192

typedef __attribute__((ext_vector_type(4))) float  f32x4;
typedef __attribute__((ext_vector_type(8))) __bf16 bf16x8;
typedef __attribute__((ext_vector_type(4))) __bf16 bf16x4;

#define MAXROWS  17408   // 16384 assignments + 8*128 padding
#define MAXTILES 136     // 16384/128 + 8

// ---- ws layout (bytes) ----
#define WS_COUNTS  0        // int[8*32]  spread counters
#define WS_CURSORS 1024     // int[8]
#define WS_SSUM    1056     // float[8*32]
#define WS_NTILES  2080     // int
#define WS_BASE    2084     // int[8]
#define WS_TILE_E  2176     // int[160]
#define WS_TILE_RB 2816     // int[160]
#define WS_TKIDX   4096     // int[2*TTOK]
#define WS_TKW     69632    // float[2*TTOK]
#define WS_TOKID   135168   // int[MAXROWS]
#define WS_ROWW    204800   // float[MAXROWS]
#define WS_H       274432   // __bf16[MAXROWS][ffc]

__device__ inline f32x4 fzero() { f32x4 v = {0.f, 0.f, 0.f, 0.f}; return v; }

// ---------------- gating: logits -> softmax -> top2 -> weights + stats ----------------
__global__ __launch_bounds__(256) void gate_kernel(
    const float* __restrict__ x, const float* __restrict__ gW, const float* __restrict__ gb,
    int* counts, float* ssum, int* tk_idx, float* tk_w)
{
    int wave = threadIdx.x >> 6;
    int lane = threadIdx.x & 63;
    int t = blockIdx.x * 4 + wave;      // grid = 2048 -> t < 8192

    float acc[NE];
#pragma unroll
    for (int e = 0; e < NE; e++) acc[e] = 0.f;

    const float* xr = x + (size_t)t * EMB;
#pragma unroll
    for (int i = 0; i < 4; i++) {
        int d0 = i * 256 + lane * 4;
        f32x4 xv = *(const f32x4*)(xr + d0);
#pragma unroll
        for (int j = 0; j < 4; j++) {
            const float* wrow = gW + (size_t)(d0 + j) * NE;
            float xs = xv[j];
#pragma unroll
            for (int e = 0; e < NE; e++) acc[e] += xs * wrow[e];
        }
    }
#pragma unroll
    for (int e = 0; e < NE; e++) {
#pragma unroll
        for (int off = 32; off; off >>= 1) acc[e] += __shfl_xor(acc[e], off, 64);
    }
    if (lane == 0) {
        float sc[NE];
        float m = -1e30f;
        for (int e = 0; e < NE; e++) { sc[e] = acc[e] + gb[e]; m = fmaxf(m, sc[e]); }
        float sum = 0.f;
        for (int e = 0; e < NE; e++) { sc[e] = expf(sc[e] - m); sum += sc[e]; }
        float inv = 1.f / sum;
        for (int e = 0; e < NE; e++) sc[e] *= inv;
        // top-2, first occurrence wins ties (matches jax.lax.top_k)
        int i0 = 0; float s0 = sc[0];
        for (int e = 1; e < NE; e++) if (sc[e] > s0) { s0 = sc[e]; i0 = e; }
        int i1 = -1; float s1 = -1e30f;
        for (int e = 0; e < NE; e++) if (e != i0 && sc[e] > s1) { s1 = sc[e]; i1 = e; }
        float rn = 1.f / (s0 + s1);
        tk_idx[2 * t]     = i0;  tk_idx[2 * t + 1] = i1;
        tk_w[2 * t]       = s0 * rn;  tk_w[2 * t + 1] = s1 * rn;
        int slot = blockIdx.x & 31;
        atomicAdd(&counts[i0 * 32 + slot], 1);
        atomicAdd(&counts[i1 * 32 + slot], 1);
        for (int e = 0; e < NE; e++) atomicAdd(&ssum[e * 32 + slot], sc[e]);
    }
}

// ---------------- build padded per-expert segments + tile table + aux loss ----------------
__global__ void route_build_kernel(const int* counts, const float* ssum,
                                   int* ntiles, int* base, int* tile_e, int* tile_rb,
                                   float* out_aux)
{
    if (threadIdx.x != 0 || blockIdx.x != 0) return;
    int total = 0, tiles = 0;
    float aux = 0.f;
    for (int e = 0; e < NE; e++) {
        int c = 0; float ss = 0.f;
        for (int j = 0; j < 32; j++) { c += counts[e * 32 + j]; ss += ssum[e * 32 + j]; }
        base[e] = total;
        int nt = (c + 127) >> 7;
        for (int i = 0; i < nt; i++) { tile_e[tiles] = e; tile_rb[tiles] = total + (i << 7); tiles++; }
        total += nt << 7;
        aux += ((float)c / (float)(TTOK * 2)) * (ss / (float)TTOK);
    }
    *ntiles = tiles;
    *out_aux = aux * (float)NE;
}

// ---------------- scatter assignments into expert segments ----------------
__global__ __launch_bounds__(256) void scatter_kernel(
    const int* __restrict__ tk_idx, const float* __restrict__ tk_w,
    const int* __restrict__ base, int* cursors, int* token_id, float* roww)
{
    int t = blockIdx.x * 256 + threadIdx.x;
#pragma unroll
    for (int k = 0; k < 2; k++) {
        int e = tk_idx[2 * t + k];
        int pos = atomicAdd(&cursors[e], 1);
        int slot = base[e] + pos;
        token_id[slot] = t;
        roww[slot] = tk_w[2 * t + k];
    }
}

// ---------------- out = sum_k w_k * b2[e_k]  (bias pre-accumulate) ----------------
__global__ __launch_bounds__(256) void out_init_kernel(
    const int* __restrict__ tk_idx, const float* __restrict__ tk_w,
    const float* __restrict__ b2, float* __restrict__ out)
{
    int t = blockIdx.x;
    int dq = threadIdx.x * 4;
    int e0 = tk_idx[2 * t], e1 = tk_idx[2 * t + 1];
    float w0 = tk_w[2 * t], w1 = tk_w[2 * t + 1];
    f32x4 a = *(const f32x4*)(b2 + (size_t)e0 * EMB + dq);
    f32x4 b = *(const f32x4*)(b2 + (size_t)e1 * EMB + dq);
    f32x4 r;
#pragma unroll
    for (int q = 0; q < 4; q++) r[q] = w0 * a[q] + w1 * b[q];
    *(f32x4*)(out + (size_t)t * EMB + dq) = r;
}

// ---------------- grouped GEMM1: h = gelu(x[tok] @ W1[e] + b1[e]) -> bf16 ----------------
__global__ __launch_bounds__(256) void gemm1_kernel(
    const float* __restrict__ x, const float* __restrict__ W1, const float* __restrict__ b1,
    const int* __restrict__ token_id, const int* __restrict__ tile_e, const int* __restrict__ tile_rb,
    const int* __restrict__ ntiles, __bf16* __restrict__ h, int ffc, int chunk)
{
    int mt = blockIdx.x;
    if (mt >= *ntiles) return;
    int e  = tile_e[mt];
    int rb = tile_rb[mt];
    int n0loc = blockIdx.y * 128;

    const float* Bbase = W1 + (size_t)e * EMB * FF + (size_t)chunk * ffc + n0loc;
    const float* b1g   = b1 + (size_t)e * FF + (size_t)chunk * ffc + n0loc;

    __shared__ __bf16 As[128 * 40];   // [row][k], stride 40 (80B, 16B-aligned rows)
    __shared__ __bf16 Bs[128 * 40];   // [n][k] transposed

    int tid = threadIdx.x, lane = tid & 63, wave = tid >> 6;
    int wr = wave >> 1, wc = wave & 1;

    int arow = tid >> 1;
    int kb = (tid & 1) * 16;
    int tok = token_id[rb + arow];
    const float* asrc = (tok >= 0) ? (x + (size_t)tok * EMB + kb) : (const float*)0;

    int bk = tid >> 3;              // 0..31
    int nb = (tid & 7) * 16;        // 0..112

    f32x4 acc[4][4];
#pragma unroll
    for (int i = 0; i < 4; i++)
#pragma unroll
        for (int j = 0; j < 4; j++) acc[i][j] = fzero();

    int cl = lane & 15;
    int k8 = (lane >> 4) * 8;

    for (int k0 = 0; k0 < EMB; k0 += 32) {
        // stage A (gathered x, fp32 -> bf16)
#pragma unroll
        for (int j = 0; j < 4; j++) {
            f32x4 v = fzero();
            if (asrc) v = *(const f32x4*)(asrc + k0 + j * 4);
            bf16x4 s;
#pragma unroll
            for (int q = 0; q < 4; q++) s[q] = (__bf16)v[q];
            *(bf16x4*)&As[arow * 40 + kb + j * 4] = s;
        }
        // stage B transposed (W1 rows k, cols n)
        const float* bs = Bbase + (size_t)(k0 + bk) * FF + nb;
#pragma unroll
        for (int j = 0; j < 4; j++) {
            f32x4 v = *(const f32x4*)(bs + j * 4);
#pragma unroll
            for (int q = 0; q < 4; q++) Bs[(nb + j * 4 + q) * 40 + bk] = (__bf16)v[q];
        }
        __syncthreads();

        bf16x8 af[4], bfr[4];
#pragma unroll
        for (int mi = 0; mi < 4; mi++) af[mi] = *(bf16x8*)&As[(wr * 64 + mi * 16 + cl) * 40 + k8];
#pragma unroll
        for (int ni = 0; ni < 4; ni++) bfr[ni] = *(bf16x8*)&Bs[(wc * 64 + ni * 16 + cl) * 40 + k8];
#pragma unroll
        for (int mi = 0; mi < 4; mi++)
#pragma unroll
            for (int ni = 0; ni < 4; ni++)
                acc[mi][ni] = __builtin_amdgcn_mfma_f32_16x16x32_bf16(af[mi], bfr[ni], acc[mi][ni], 0, 0, 0);
        __syncthreads();
    }

    // epilogue: bias + exact gelu -> bf16 h
    int r0 = (lane >> 4) * 4;
#pragma unroll
    for (int mi = 0; mi < 4; mi++) {
#pragma unroll
        for (int ni = 0; ni < 4; ni++) {
            int col = wc * 64 + ni * 16 + cl;
            float bias = b1g[col];
#pragma unroll
            for (int j = 0; j < 4; j++) {
                int row = wr * 64 + mi * 16 + r0 + j;
                float v = acc[mi][ni][j] + bias;
                v = 0.5f * v * (1.0f + erff(v * 0.70710678118654752f));
                h[(size_t)(rb + row) * ffc + n0loc + col] = (__bf16)v;
            }
        }
    }
}

// ---------------- grouped GEMM2: out[tok] += w * (h @ W2[e]) ----------------
__global__ __launch_bounds__(256) void gemm2_kernel(
    const __bf16* __restrict__ h, const float* __restrict__ W2,
    const int* __restrict__ token_id, const float* __restrict__ roww,
    const int* __restrict__ tile_e, const int* __restrict__ tile_rb,
    const int* __restrict__ ntiles, float* __restrict__ out, int ffc, int chunk)
{
    int mt = blockIdx.x;
    if (mt >= *ntiles) return;
    int e  = tile_e[mt];
    int rb = tile_rb[mt];
    int n0 = blockIdx.y * 128;

    const float* Bbase = W2 + (size_t)e * FF * EMB + (size_t)chunk * ffc * EMB + n0;

    __shared__ __bf16 As[128 * 40];
    __shared__ __bf16 Bs[128 * 40];

    int tid = threadIdx.x, lane = tid & 63, wave = tid >> 6;
    int wr = wave >> 1, wc = wave & 1;

    int arow = tid >> 1;
    int half = tid & 1;
    const __bf16* hrow = h + (size_t)(rb + arow) * ffc + half * 16;

    int bk = tid >> 3;
    int nb = (tid & 7) * 16;

    f32x4 acc[4][4];
#pragma unroll
    for (int i = 0; i < 4; i++)
#pragma unroll
        for (int j = 0; j < 4; j++) acc[i][j] = fzero();

    int cl = lane & 15;
    int k8 = (lane >> 4) * 8;

    for (int k0 = 0; k0 < ffc; k0 += 32) {
        // stage A (bf16 h rows, direct 16B copies)
        uint4 v0 = *(const uint4*)(hrow + k0);
        uint4 v1 = *(const uint4*)(hrow + k0 + 8);
        *(uint4*)&As[arow * 40 + half * 16] = v0;
        *(uint4*)&As[arow * 40 + half * 16 + 8] = v1;
        // stage B transposed (W2 rows k, cols n)
        const float* bs = Bbase + (size_t)(k0 + bk) * EMB + nb;
#pragma unroll
        for (int j = 0; j < 4; j++) {
            f32x4 v = *(const f32x4*)(bs + j * 4);
#pragma unroll
            for (int q = 0; q < 4; q++) Bs[(nb + j * 4 + q) * 40 + bk] = (__bf16)v[q];
        }
        __syncthreads();

        bf16x8 af[4], bfr[4];
#pragma unroll
        for (int mi = 0; mi < 4; mi++) af[mi] = *(bf16x8*)&As[(wr * 64 + mi * 16 + cl) * 40 + k8];
#pragma unroll
        for (int ni = 0; ni < 4; ni++) bfr[ni] = *(bf16x8*)&Bs[(wc * 64 + ni * 16 + cl) * 40 + k8];
#pragma unroll
        for (int mi = 0; mi < 4; mi++)
#pragma unroll
            for (int ni = 0; ni < 4; ni++)
                acc[mi][ni] = __builtin_amdgcn_mfma_f32_16x16x32_bf16(af[mi], bfr[ni], acc[mi][ni], 0, 0, 0);
        __syncthreads();
    }

    int r0 = (lane >> 4) * 4;
#pragma unroll
    for (int mi = 0; mi < 4; mi++) {
#pragma unroll
        for (int ni = 0; ni < 4; ni++) {
            int col = wc * 64 + ni * 16 + cl;
#pragma unroll
            for (int j = 0; j < 4; j++) {
                int row = wr * 64 + mi * 16 + r0 + j;
                int gr = rb + row;
                int tok = token_id[gr];
                if (tok >= 0)
                    atomicAdd(out + (size_t)tok * EMB + n0 + col, roww[gr] * acc[mi][ni][j]);
            }
        }
    }
}

extern "C" void kernel_launch(void* const* d_in, const int* in_sizes, int n_in,
                              void* d_out, int out_size, void* d_ws, size_t ws_size,
                              hipStream_t stream)
{
    const float* x   = (const float*)d_in[0];
    const float* gW  = (const float*)d_in[1];
    const float* gb  = (const float*)d_in[2];
    const float* W1  = (const float*)d_in[3];
    const float* b1  = (const float*)d_in[4];
    const float* W2  = (const float*)d_in[5];
    const float* b2  = (const float*)d_in[6];
    float* out = (float*)d_out;

    char* ws = (char*)d_ws;
    int*   counts  = (int*)(ws + WS_COUNTS);
    int*   cursors = (int*)(ws + WS_CURSORS);
    float* ssum    = (float*)(ws + WS_SSUM);
    int*   ntiles  = (int*)(ws + WS_NTILES);
    int*   base    = (int*)(ws + WS_BASE);
    int*   tile_e  = (int*)(ws + WS_TILE_E);
    int*   tile_rb = (int*)(ws + WS_TILE_RB);
    int*   tk_idx  = (int*)(ws + WS_TKIDX);
    float* tk_w    = (float*)(ws + WS_TKW);
    int*   token_id= (int*)(ws + WS_TOKID);
    float* roww    = (float*)(ws + WS_ROWW);
    __bf16* hbuf   = (__bf16*)(ws + WS_H);

    // pick FF chunk width by available workspace (h = MAXROWS x ffc bf16)
    int ffc = 512;
    if      (ws_size >= (size_t)WS_H + (size_t)MAXROWS * 4096 * 2) ffc = 4096;
    else if (ws_size >= (size_t)WS_H + (size_t)MAXROWS * 2048 * 2) ffc = 2048;
    else if (ws_size >= (size_t)WS_H + (size_t)MAXROWS * 1024 * 2) ffc = 1024;

    hipMemsetAsync(ws + WS_COUNTS, 0, 2080, stream);                 // counts+cursors+ssum
    hipMemsetAsync(ws + WS_TOKID, 0xFF, (size_t)MAXROWS * 4, stream); // token_id = -1

    gate_kernel<<<TTOK / 4, 256, 0, stream>>>(x, gW, gb, counts, ssum, tk_idx, tk_w);
    route_build_kernel<<<1, 64, 0, stream>>>(counts, ssum, ntiles, base, tile_e, tile_rb,
                                             out + (size_t)TTOK * EMB);
    scatter_kernel<<<TTOK / 256, 256, 0, stream>>>(tk_idx, tk_w, base, cursors, token_id, roww);
    out_init_kernel<<<TTOK, 256, 0, stream>>>(tk_idx, tk_w, b2, out);

    int nchunks = FF / ffc;
    for (int c = 0; c < nchunks; c++) {
        gemm1_kernel<<<dim3(MAXTILES, ffc / 128), 256, 0, stream>>>(
            x, W1, b1, token_id, tile_e, tile_rb, ntiles, hbuf, ffc, c);
        gemm2_kernel<<<dim3(MAXTILES, EMB / 128), 256, 0, stream>>>(
            hbuf, W2, token_id, roww, tile_e, tile_rb, ntiles, out, ffc, c);
    }
}

// Round 2
// 921.067 us; speedup vs baseline: 1.3841x; 1.3841x over previous
//
#include <hip/hip_runtime.h>
#include <math.h>

#define EMB 1024
#define FF  4096
#define NE  8
#define TTOK 8192

typedef __attribute__((ext_vector_type(4))) float  f32x4;
typedef __attribute__((ext_vector_type(8))) __bf16 bf16x8;
typedef __attribute__((ext_vector_type(4))) __bf16 bf16x4;

#define MAXROWS  17408   // 16384 assignments + 8*128 padding
#define MAXTILES 136     // 16384/128 + 8

// ---- ws layout (bytes) ----
#define WS_COUNTS  0        // int[8*32]
#define WS_CURSORS 1024     // int[8]
#define WS_SSUM    1056     // float[8*32]
#define WS_NTILES  2080     // int
#define WS_BASE    2084     // int[8]
#define WS_TILE_E  2176     // int[160]
#define WS_TILE_RB 2816     // int[160]
#define WS_TKIDX   4096     // int[2*TTOK]
#define WS_TKW     69632    // float[2*TTOK]
#define WS_TOKID   135168   // int[MAXROWS]
#define WS_ROWW    204800   // float[MAXROWS]
#define WS_BIG     274432   // variable region

#define SZ_W1T ((size_t)NE * EMB * FF * 2)   // 67108864
#define SZ_W2T ((size_t)NE * EMB * FF * 2)   // 67108864
#define SZ_XB  ((size_t)TTOK * EMB * 2)      // 16777216

__device__ inline f32x4 fzero() { f32x4 v = {0.f, 0.f, 0.f, 0.f}; return v; }

// ---------------- gating ----------------
__global__ __launch_bounds__(256) void gate_kernel(
    const float* __restrict__ x, const float* __restrict__ gW, const float* __restrict__ gb,
    int* counts, float* ssum, int* tk_idx, float* tk_w)
{
    int wave = threadIdx.x >> 6;
    int lane = threadIdx.x & 63;
    int t = blockIdx.x * 4 + wave;

    float acc[NE];
#pragma unroll
    for (int e = 0; e < NE; e++) acc[e] = 0.f;

    const float* xr = x + (size_t)t * EMB;
#pragma unroll
    for (int i = 0; i < 4; i++) {
        int d0 = i * 256 + lane * 4;
        f32x4 xv = *(const f32x4*)(xr + d0);
#pragma unroll
        for (int j = 0; j < 4; j++) {
            const float* wrow = gW + (size_t)(d0 + j) * NE;
            float xs = xv[j];
#pragma unroll
            for (int e = 0; e < NE; e++) acc[e] += xs * wrow[e];
        }
    }
#pragma unroll
    for (int e = 0; e < NE; e++) {
#pragma unroll
        for (int off = 32; off; off >>= 1) acc[e] += __shfl_xor(acc[e], off, 64);
    }
    if (lane == 0) {
        float sc[NE];
        float m = -1e30f;
        for (int e = 0; e < NE; e++) { sc[e] = acc[e] + gb[e]; m = fmaxf(m, sc[e]); }
        float sum = 0.f;
        for (int e = 0; e < NE; e++) { sc[e] = expf(sc[e] - m); sum += sc[e]; }
        float inv = 1.f / sum;
        for (int e = 0; e < NE; e++) sc[e] *= inv;
        int i0 = 0; float s0 = sc[0];
        for (int e = 1; e < NE; e++) if (sc[e] > s0) { s0 = sc[e]; i0 = e; }
        int i1 = -1; float s1 = -1e30f;
        for (int e = 0; e < NE; e++) if (e != i0 && sc[e] > s1) { s1 = sc[e]; i1 = e; }
        float rn = 1.f / (s0 + s1);
        tk_idx[2 * t]     = i0;  tk_idx[2 * t + 1] = i1;
        tk_w[2 * t]       = s0 * rn;  tk_w[2 * t + 1] = s1 * rn;
        int slot = blockIdx.x & 31;
        atomicAdd(&counts[i0 * 32 + slot], 1);
        atomicAdd(&counts[i1 * 32 + slot], 1);
        for (int e = 0; e < NE; e++) atomicAdd(&ssum[e * 32 + slot], sc[e]);
    }
}

// ---------------- routing tables + aux ----------------
__global__ void route_build_kernel(const int* counts, const float* ssum,
                                   int* ntiles, int* base, int* tile_e, int* tile_rb,
                                   float* out_aux)
{
    if (threadIdx.x != 0 || blockIdx.x != 0) return;
    int total = 0, tiles = 0;
    float aux = 0.f;
    for (int e = 0; e < NE; e++) {
        int c = 0; float ss = 0.f;
        for (int j = 0; j < 32; j++) { c += counts[e * 32 + j]; ss += ssum[e * 32 + j]; }
        base[e] = total;
        int nt = (c + 127) >> 7;
        for (int i = 0; i < nt; i++) { tile_e[tiles] = e; tile_rb[tiles] = total + (i << 7); tiles++; }
        total += nt << 7;
        aux += ((float)c / (float)(TTOK * 2)) * (ss / (float)TTOK);
    }
    *ntiles = tiles;
    *out_aux = aux * (float)NE;
}

__global__ __launch_bounds__(256) void scatter_kernel(
    const int* __restrict__ tk_idx, const float* __restrict__ tk_w,
    const int* __restrict__ base, int* cursors, int* token_id, float* roww)
{
    int t = blockIdx.x * 256 + threadIdx.x;
#pragma unroll
    for (int k = 0; k < 2; k++) {
        int e = tk_idx[2 * t + k];
        int pos = atomicAdd(&cursors[e], 1);
        int slot = base[e] + pos;
        token_id[slot] = t;
        roww[slot] = tk_w[2 * t + k];
    }
}

__global__ __launch_bounds__(256) void out_init_kernel(
    const int* __restrict__ tk_idx, const float* __restrict__ tk_w,
    const float* __restrict__ b2, float* __restrict__ out)
{
    int t = blockIdx.x;
    int dq = threadIdx.x * 4;
    int e0 = tk_idx[2 * t], e1 = tk_idx[2 * t + 1];
    float w0 = tk_w[2 * t], w1 = tk_w[2 * t + 1];
    f32x4 a = *(const f32x4*)(b2 + (size_t)e0 * EMB + dq);
    f32x4 b = *(const f32x4*)(b2 + (size_t)e1 * EMB + dq);
    f32x4 r;
#pragma unroll
    for (int q = 0; q < 4; q++) r[q] = w0 * a[q] + w1 * b[q];
    *(f32x4*)(out + (size_t)t * EMB + dq) = r;
}

// ---------------- converts ----------------
__global__ __launch_bounds__(256) void cvt_x_kernel(const float* __restrict__ x, __bf16* __restrict__ xb)
{
    size_t i = ((size_t)blockIdx.x * 256 + threadIdx.x) * 8;
    f32x4 a = *(const f32x4*)(x + i);
    f32x4 b = *(const f32x4*)(x + i + 4);
    bf16x8 o;
#pragma unroll
    for (int q = 0; q < 4; q++) { o[q] = (__bf16)a[q]; o[q + 4] = (__bf16)b[q]; }
    *(bf16x8*)(xb + i) = o;
}

// in [R][C] fp32 per expert -> out [C][R] bf16 per expert. grid (R/64, C/64, NE)
__global__ __launch_bounds__(256) void transpose_cvt_kernel(
    const float* __restrict__ in, __bf16* __restrict__ outb, int R, int C)
{
    int e = blockIdx.z;
    const float* src = in + (size_t)e * R * C;
    __bf16* dst = outb + (size_t)e * R * C;
    __shared__ __bf16 Ls[64 * 72];
    int t = threadIdx.x;
    int r0 = blockIdx.x * 64, c0 = blockIdx.y * 64;
    int ri = t >> 4, cj = (t & 15) * 4;
#pragma unroll
    for (int p = 0; p < 4; p++) {
        int r = ri + p * 16;
        f32x4 v = *(const f32x4*)(src + (size_t)(r0 + r) * C + c0 + cj);
#pragma unroll
        for (int q = 0; q < 4; q++) Ls[(cj + q) * 72 + r] = (__bf16)v[q];
    }
    __syncthreads();
    int c = t >> 2, rq = (t & 3) * 16;
    bf16x8 a = *(bf16x8*)&Ls[c * 72 + rq];
    bf16x8 b = *(bf16x8*)&Ls[c * 72 + rq + 8];
    *(bf16x8*)(dst + (size_t)(c0 + c) * R + r0 + rq) = a;
    *(bf16x8*)(dst + (size_t)(c0 + c) * R + r0 + rq + 8) = b;
}

// ---------------- grouped GEMM1: h = gelu(x[tok] @ W1[e] + b1[e]) ----------------
// FAST: A from xb (bf16), B from W1T[e][f][d] (bf16, k-minor). SLOW: round-1 staging.
template <bool FAST>
__global__ __launch_bounds__(256) void gemm1_kernel(
    const float* __restrict__ x, const __bf16* __restrict__ xb,
    const float* __restrict__ W1, const __bf16* __restrict__ W1T,
    const float* __restrict__ b1,
    const int* __restrict__ token_id, const int* __restrict__ tile_e, const int* __restrict__ tile_rb,
    const int* __restrict__ ntiles, __bf16* __restrict__ h, int ffc, int chunk)
{
    int mt = blockIdx.x;
    if (mt >= *ntiles) return;
    int e  = tile_e[mt];
    int rb = tile_rb[mt];
    int n0loc = blockIdx.y * 128;

    const float* b1g = b1 + (size_t)e * FF + (size_t)chunk * ffc + n0loc;

    __shared__ __bf16 As[128 * 40];
    __shared__ __bf16 Bs[128 * 40];

    int tid = threadIdx.x, lane = tid & 63, wave = tid >> 6;
    int wr = wave >> 1, wc = wave & 1;

    int arow = tid >> 1;
    int half = tid & 1;
    int tok = token_id[rb + arow];

    f32x4 acc[4][4];
#pragma unroll
    for (int i = 0; i < 4; i++)
#pragma unroll
        for (int j = 0; j < 4; j++) acc[i][j] = fzero();

    int cl = lane & 15;
    int k8 = (lane >> 4) * 8;

    if (FAST) {
        const __bf16* asrc = (tok >= 0) ? (xb + (size_t)tok * EMB + half * 16) : (const __bf16*)0;
        const __bf16* bsrc = W1T + (size_t)e * FF * EMB
                           + (size_t)(chunk * ffc + n0loc + arow) * EMB + half * 16;
        for (int k0 = 0; k0 < EMB; k0 += 32) {
            uint4 a0 = {0,0,0,0}, a1 = {0,0,0,0};
            if (asrc) { a0 = *(const uint4*)(asrc + k0); a1 = *(const uint4*)(asrc + k0 + 8); }
            uint4 b0 = *(const uint4*)(bsrc + k0);
            uint4 b1v = *(const uint4*)(bsrc + k0 + 8);
            *(uint4*)&As[arow * 40 + half * 16]     = a0;
            *(uint4*)&As[arow * 40 + half * 16 + 8] = a1;
            *(uint4*)&Bs[arow * 40 + half * 16]     = b0;
            *(uint4*)&Bs[arow * 40 + half * 16 + 8] = b1v;
            __syncthreads();

            bf16x8 af[4], bfr[4];
#pragma unroll
            for (int mi = 0; mi < 4; mi++) af[mi] = *(bf16x8*)&As[(wr * 64 + mi * 16 + cl) * 40 + k8];
#pragma unroll
            for (int ni = 0; ni < 4; ni++) bfr[ni] = *(bf16x8*)&Bs[(wc * 64 + ni * 16 + cl) * 40 + k8];
#pragma unroll
            for (int mi = 0; mi < 4; mi++)
#pragma unroll
                for (int ni = 0; ni < 4; ni++)
                    acc[mi][ni] = __builtin_amdgcn_mfma_f32_16x16x32_bf16(af[mi], bfr[ni], acc[mi][ni], 0, 0, 0);
            __syncthreads();
        }
    } else {
        const float* asrc = (tok >= 0) ? (x + (size_t)tok * EMB + half * 16) : (const float*)0;
        const float* Bbase = W1 + (size_t)e * EMB * FF + (size_t)chunk * ffc + n0loc;
        int bk = tid >> 3;
        int nb = (tid & 7) * 16;
        for (int k0 = 0; k0 < EMB; k0 += 32) {
#pragma unroll
            for (int j = 0; j < 2; j++) {
                f32x4 v = fzero();
                if (asrc) v = *(const f32x4*)(asrc + k0 + j * 4 + (half ? 0 : 0));
                // preserve round-1 semantics: two f32x4 per 16-elem half
                v = asrc ? *(const f32x4*)(asrc + k0 + j * 4) : fzero();
                bf16x4 s;
#pragma unroll
                for (int q = 0; q < 4; q++) s[q] = (__bf16)v[q];
                *(bf16x4*)&As[arow * 40 + half * 16 + j * 4] = s;
                f32x4 v2 = asrc ? *(const f32x4*)(asrc + k0 + 8 + j * 4) : fzero();
                bf16x4 s2;
#pragma unroll
                for (int q = 0; q < 4; q++) s2[q] = (__bf16)v2[q];
                *(bf16x4*)&As[arow * 40 + half * 16 + 8 + j * 4] = s2;
            }
            const float* bs = Bbase + (size_t)(k0 + bk) * FF + nb;
#pragma unroll
            for (int j = 0; j < 4; j++) {
                f32x4 v = *(const f32x4*)(bs + j * 4);
#pragma unroll
                for (int q = 0; q < 4; q++) Bs[(nb + j * 4 + q) * 40 + bk] = (__bf16)v[q];
            }
            __syncthreads();

            bf16x8 af[4], bfr[4];
#pragma unroll
            for (int mi = 0; mi < 4; mi++) af[mi] = *(bf16x8*)&As[(wr * 64 + mi * 16 + cl) * 40 + k8];
#pragma unroll
            for (int ni = 0; ni < 4; ni++) bfr[ni] = *(bf16x8*)&Bs[(wc * 64 + ni * 16 + cl) * 40 + k8];
#pragma unroll
            for (int mi = 0; mi < 4; mi++)
#pragma unroll
                for (int ni = 0; ni < 4; ni++)
                    acc[mi][ni] = __builtin_amdgcn_mfma_f32_16x16x32_bf16(af[mi], bfr[ni], acc[mi][ni], 0, 0, 0);
            __syncthreads();
        }
    }

    int r0 = (lane >> 4) * 4;
#pragma unroll
    for (int mi = 0; mi < 4; mi++) {
#pragma unroll
        for (int ni = 0; ni < 4; ni++) {
            int col = wc * 64 + ni * 16 + cl;
            float bias = b1g[col];
#pragma unroll
            for (int j = 0; j < 4; j++) {
                int row = wr * 64 + mi * 16 + r0 + j;
                float v = acc[mi][ni][j] + bias;
                v = 0.5f * v * (1.0f + erff(v * 0.70710678118654752f));
                h[(size_t)(rb + row) * ffc + n0loc + col] = (__bf16)v;
            }
        }
    }
}

// ---------------- grouped GEMM2: out[tok] += w * (h @ W2[e]) ----------------
template <bool FAST>
__global__ __launch_bounds__(256) void gemm2_kernel(
    const __bf16* __restrict__ h,
    const float* __restrict__ W2, const __bf16* __restrict__ W2T,
    const int* __restrict__ token_id, const float* __restrict__ roww,
    const int* __restrict__ tile_e, const int* __restrict__ tile_rb,
    const int* __restrict__ ntiles, float* __restrict__ out, int ffc, int chunk)
{
    int mt = blockIdx.x;
    if (mt >= *ntiles) return;
    int e  = tile_e[mt];
    int rb = tile_rb[mt];
    int n0 = blockIdx.y * 128;

    __shared__ __bf16 As[128 * 40];
    __shared__ __bf16 Bs[128 * 40];

    int tid = threadIdx.x, lane = tid & 63, wave = tid >> 6;
    int wr = wave >> 1, wc = wave & 1;

    int arow = tid >> 1;
    int half = tid & 1;
    const __bf16* hrow = h + (size_t)(rb + arow) * ffc + half * 16;

    f32x4 acc[4][4];
#pragma unroll
    for (int i = 0; i < 4; i++)
#pragma unroll
        for (int j = 0; j < 4; j++) acc[i][j] = fzero();

    int cl = lane & 15;
    int k8 = (lane >> 4) * 8;

    if (FAST) {
        const __bf16* bsrc = W2T + (size_t)e * EMB * FF
                           + (size_t)(n0 + arow) * FF + chunk * ffc + half * 16;
        for (int k0 = 0; k0 < ffc; k0 += 32) {
            uint4 a0 = *(const uint4*)(hrow + k0);
            uint4 a1 = *(const uint4*)(hrow + k0 + 8);
            uint4 b0 = *(const uint4*)(bsrc + k0);
            uint4 b1v = *(const uint4*)(bsrc + k0 + 8);
            *(uint4*)&As[arow * 40 + half * 16]     = a0;
            *(uint4*)&As[arow * 40 + half * 16 + 8] = a1;
            *(uint4*)&Bs[arow * 40 + half * 16]     = b0;
            *(uint4*)&Bs[arow * 40 + half * 16 + 8] = b1v;
            __syncthreads();

            bf16x8 af[4], bfr[4];
#pragma unroll
            for (int mi = 0; mi < 4; mi++) af[mi] = *(bf16x8*)&As[(wr * 64 + mi * 16 + cl) * 40 + k8];
#pragma unroll
            for (int ni = 0; ni < 4; ni++) bfr[ni] = *(bf16x8*)&Bs[(wc * 64 + ni * 16 + cl) * 40 + k8];
#pragma unroll
            for (int mi = 0; mi < 4; mi++)
#pragma unroll
                for (int ni = 0; ni < 4; ni++)
                    acc[mi][ni] = __builtin_amdgcn_mfma_f32_16x16x32_bf16(af[mi], bfr[ni], acc[mi][ni], 0, 0, 0);
            __syncthreads();
        }
    } else {
        const float* Bbase = W2 + (size_t)e * FF * EMB + (size_t)chunk * ffc * EMB + n0;
        int bk = tid >> 3;
        int nb = (tid & 7) * 16;
        for (int k0 = 0; k0 < ffc; k0 += 32) {
            uint4 v0 = *(const uint4*)(hrow + k0);
            uint4 v1 = *(const uint4*)(hrow + k0 + 8);
            *(uint4*)&As[arow * 40 + half * 16] = v0;
            *(uint4*)&As[arow * 40 + half * 16 + 8] = v1;
            const float* bs = Bbase + (size_t)(k0 + bk) * EMB + nb;
#pragma unroll
            for (int j = 0; j < 4; j++) {
                f32x4 v = *(const f32x4*)(bs + j * 4);
#pragma unroll
                for (int q = 0; q < 4; q++) Bs[(nb + j * 4 + q) * 40 + bk] = (__bf16)v[q];
            }
            __syncthreads();

            bf16x8 af[4], bfr[4];
#pragma unroll
            for (int mi = 0; mi < 4; mi++) af[mi] = *(bf16x8*)&As[(wr * 64 + mi * 16 + cl) * 40 + k8];
#pragma unroll
            for (int ni = 0; ni < 4; ni++) bfr[ni] = *(bf16x8*)&Bs[(wc * 64 + ni * 16 + cl) * 40 + k8];
#pragma unroll
            for (int mi = 0; mi < 4; mi++)
#pragma unroll
                for (int ni = 0; ni < 4; ni++)
                    acc[mi][ni] = __builtin_amdgcn_mfma_f32_16x16x32_bf16(af[mi], bfr[ni], acc[mi][ni], 0, 0, 0);
            __syncthreads();
        }
    }

    int r0 = (lane >> 4) * 4;
#pragma unroll
    for (int mi = 0; mi < 4; mi++) {
#pragma unroll
        for (int ni = 0; ni < 4; ni++) {
            int col = wc * 64 + ni * 16 + cl;
#pragma unroll
            for (int j = 0; j < 4; j++) {
                int row = wr * 64 + mi * 16 + r0 + j;
                int gr = rb + row;
                int tok = token_id[gr];
                if (tok >= 0)
                    atomicAdd(out + (size_t)tok * EMB + n0 + col, roww[gr] * acc[mi][ni][j]);
            }
        }
    }
}

extern "C" void kernel_launch(void* const* d_in, const int* in_sizes, int n_in,
                              void* d_out, int out_size, void* d_ws, size_t ws_size,
                              hipStream_t stream)
{
    const float* x   = (const float*)d_in[0];
    const float* gW  = (const float*)d_in[1];
    const float* gb  = (const float*)d_in[2];
    const float* W1  = (const float*)d_in[3];
    const float* b1  = (const float*)d_in[4];
    const float* W2  = (const float*)d_in[5];
    const float* b2  = (const float*)d_in[6];
    float* out = (float*)d_out;

    char* ws = (char*)d_ws;
    int*   counts  = (int*)(ws + WS_COUNTS);
    int*   cursors = (int*)(ws + WS_CURSORS);
    float* ssum    = (float*)(ws + WS_SSUM);
    int*   ntiles  = (int*)(ws + WS_NTILES);
    int*   base    = (int*)(ws + WS_BASE);
    int*   tile_e  = (int*)(ws + WS_TILE_E);
    int*   tile_rb = (int*)(ws + WS_TILE_RB);
    int*   tk_idx  = (int*)(ws + WS_TKIDX);
    float* tk_w    = (float*)(ws + WS_TKW);
    int*   token_id= (int*)(ws + WS_TOKID);
    float* roww    = (float*)(ws + WS_ROWW);

    auto hbytes = [](int f) { return (size_t)MAXROWS * f * 2; };

    // fast path: W1T + W2T + xb + h(ffc)
    int ffc = 0; bool fast = false;
    for (int f = 4096; f >= 256 && !fast; f >>= 1)
        if (ws_size >= WS_BIG + SZ_W1T + SZ_W2T + SZ_XB + hbytes(f)) { fast = true; ffc = f; }
    if (!fast) {
        for (int f = 4096; f >= 512 && !ffc; f >>= 1)
            if (ws_size >= WS_BIG + hbytes(f)) ffc = f;
        if (!ffc) ffc = 512;
    }

    __bf16* W1T = (__bf16*)(ws + WS_BIG);
    __bf16* W2T = (__bf16*)(ws + WS_BIG + SZ_W1T);
    __bf16* xb  = (__bf16*)(ws + WS_BIG + SZ_W1T + SZ_W2T);
    __bf16* hbuf = fast ? (__bf16*)(ws + WS_BIG + SZ_W1T + SZ_W2T + SZ_XB)
                        : (__bf16*)(ws + WS_BIG);

    hipMemsetAsync(ws + WS_COUNTS, 0, 2080, stream);
    hipMemsetAsync(ws + WS_TOKID, 0xFF, (size_t)MAXROWS * 4, stream);

    if (fast) {
        cvt_x_kernel<<<TTOK * EMB / 2048, 256, 0, stream>>>(x, xb);
        transpose_cvt_kernel<<<dim3(EMB / 64, FF / 64, NE), 256, 0, stream>>>(W1, W1T, EMB, FF);
        transpose_cvt_kernel<<<dim3(FF / 64, EMB / 64, NE), 256, 0, stream>>>(W2, W2T, FF, EMB);
    }

    gate_kernel<<<TTOK / 4, 256, 0, stream>>>(x, gW, gb, counts, ssum, tk_idx, tk_w);
    route_build_kernel<<<1, 64, 0, stream>>>(counts, ssum, ntiles, base, tile_e, tile_rb,
                                             out + (size_t)TTOK * EMB);
    scatter_kernel<<<TTOK / 256, 256, 0, stream>>>(tk_idx, tk_w, base, cursors, token_id, roww);
    out_init_kernel<<<TTOK, 256, 0, stream>>>(tk_idx, tk_w, b2, out);

    int nchunks = FF / ffc;
    for (int c = 0; c < nchunks; c++) {
        if (fast) {
            gemm1_kernel<true><<<dim3(MAXTILES, ffc / 128), 256, 0, stream>>>(
                x, xb, W1, W1T, b1, token_id, tile_e, tile_rb, ntiles, hbuf, ffc, c);
            gemm2_kernel<true><<<dim3(MAXTILES, EMB / 128), 256, 0, stream>>>(
                hbuf, W2, W2T, token_id, roww, tile_e, tile_rb, ntiles, out, ffc, c);
        } else {
            gemm1_kernel<false><<<dim3(MAXTILES, ffc / 128), 256, 0, stream>>>(
                x, xb, W1, W1T, b1, token_id, tile_e, tile_rb, ntiles, hbuf, ffc, c);
            gemm2_kernel<false><<<dim3(MAXTILES, EMB / 128), 256, 0, stream>>>(
                hbuf, W2, W2T, token_id, roww, tile_e, tile_rb, ntiles, out, ffc, c);
        }
    }
}

// Round 3
// 739.832 us; speedup vs baseline: 1.7232x; 1.2450x over previous
//
#include <hip/hip_runtime.h>
#include <math.h>

#define EMB 1024
#define FF  4096
#define NE  8
#define TTOK 8192

typedef __attribute__((ext_vector_type(4))) float  f32x4;
typedef __attribute__((ext_vector_type(8))) __bf16 bf16x8;
typedef __attribute__((ext_vector_type(4))) __bf16 bf16x4;

#define MAXROWS  17408   // 16384 assignments + 8*128 padding
#define MAXTILES 136     // 16384/128 + 8

// ---- ws layout (bytes) ----
#define WS_COUNTS  0        // int[8*32]
#define WS_CURSORS 1024     // int[8]
#define WS_SSUM    1056     // float[8*32]
#define WS_NTILES  2080     // int
#define WS_BASE    2084     // int[8]
#define WS_TILE_E  2176     // int[160]
#define WS_TILE_RB 2816     // int[160]
#define WS_TKIDX   4096     // int[2*TTOK]
#define WS_TKW     69632    // float[2*TTOK]
#define WS_TOKID   135168   // int[MAXROWS]
#define WS_ROWW    204800   // float[MAXROWS]
#define WS_SLOT    274432   // int[2*TTOK]
#define WS_ZP      339968   // __bf16[1024] zeros
#define WS_BIG2    342016   // variable region: [W1T | xb | W2T | h]

#define SZ_W1T ((size_t)NE * EMB * FF * 2)   // 64 MB
#define SZ_W2T ((size_t)NE * EMB * FF * 2)   // 64 MB
#define SZ_XB  ((size_t)TTOK * EMB * 2)      // 16 MB
#define SZ_H   ((size_t)MAXROWS * FF * 2)    // 136 MB

__device__ inline f32x4 fzero() { f32x4 v = {0.f, 0.f, 0.f, 0.f}; return v; }

__device__ __forceinline__ void gl16(const void* g, void* l) {
    __builtin_amdgcn_global_load_lds(
        (const __attribute__((address_space(1))) void*)g,
        (__attribute__((address_space(3))) void*)l, 16, 0, 0);
}

// ---------------- gating ----------------
__global__ __launch_bounds__(256) void gate_kernel(
    const float* __restrict__ x, const float* __restrict__ gW, const float* __restrict__ gb,
    int* counts, float* ssum, int* tk_idx, float* tk_w)
{
    int wave = threadIdx.x >> 6;
    int lane = threadIdx.x & 63;
    int t = blockIdx.x * 4 + wave;

    float acc[NE];
#pragma unroll
    for (int e = 0; e < NE; e++) acc[e] = 0.f;

    const float* xr = x + (size_t)t * EMB;
#pragma unroll
    for (int i = 0; i < 4; i++) {
        int d0 = i * 256 + lane * 4;
        f32x4 xv = *(const f32x4*)(xr + d0);
#pragma unroll
        for (int j = 0; j < 4; j++) {
            const float* wrow = gW + (size_t)(d0 + j) * NE;
            float xs = xv[j];
#pragma unroll
            for (int e = 0; e < NE; e++) acc[e] += xs * wrow[e];
        }
    }
#pragma unroll
    for (int e = 0; e < NE; e++) {
#pragma unroll
        for (int off = 32; off; off >>= 1) acc[e] += __shfl_xor(acc[e], off, 64);
    }
    if (lane == 0) {
        float sc[NE];
        float m = -1e30f;
        for (int e = 0; e < NE; e++) { sc[e] = acc[e] + gb[e]; m = fmaxf(m, sc[e]); }
        float sum = 0.f;
        for (int e = 0; e < NE; e++) { sc[e] = expf(sc[e] - m); sum += sc[e]; }
        float inv = 1.f / sum;
        for (int e = 0; e < NE; e++) sc[e] *= inv;
        int i0 = 0; float s0 = sc[0];
        for (int e = 1; e < NE; e++) if (sc[e] > s0) { s0 = sc[e]; i0 = e; }
        int i1 = -1; float s1 = -1e30f;
        for (int e = 0; e < NE; e++) if (e != i0 && sc[e] > s1) { s1 = sc[e]; i1 = e; }
        float rn = 1.f / (s0 + s1);
        tk_idx[2 * t]     = i0;  tk_idx[2 * t + 1] = i1;
        tk_w[2 * t]       = s0 * rn;  tk_w[2 * t + 1] = s1 * rn;
        int slot = blockIdx.x & 31;
        atomicAdd(&counts[i0 * 32 + slot], 1);
        atomicAdd(&counts[i1 * 32 + slot], 1);
        for (int e = 0; e < NE; e++) atomicAdd(&ssum[e * 32 + slot], sc[e]);
    }
}

// ---------------- routing tables + aux ----------------
__global__ void route_build_kernel(const int* counts, const float* ssum,
                                   int* ntiles, int* base, int* tile_e, int* tile_rb,
                                   float* out_aux)
{
    if (threadIdx.x != 0 || blockIdx.x != 0) return;
    int total = 0, tiles = 0;
    float aux = 0.f;
    for (int e = 0; e < NE; e++) {
        int c = 0; float ss = 0.f;
        for (int j = 0; j < 32; j++) { c += counts[e * 32 + j]; ss += ssum[e * 32 + j]; }
        base[e] = total;
        int nt = (c + 127) >> 7;
        for (int i = 0; i < nt; i++) { tile_e[tiles] = e; tile_rb[tiles] = total + (i << 7); tiles++; }
        total += nt << 7;
        aux += ((float)c / (float)(TTOK * 2)) * (ss / (float)TTOK);
    }
    *ntiles = tiles;
    *out_aux = aux * (float)NE;
}

__global__ __launch_bounds__(256) void scatter_kernel(
    const int* __restrict__ tk_idx, const float* __restrict__ tk_w,
    const int* __restrict__ base, int* cursors, int* token_id, float* roww,
    int* slot_of)
{
    int t = blockIdx.x * 256 + threadIdx.x;
#pragma unroll
    for (int k = 0; k < 2; k++) {
        int e = tk_idx[2 * t + k];
        int pos = atomicAdd(&cursors[e], 1);
        int slot = base[e] + pos;
        token_id[slot] = t;
        roww[slot] = tk_w[2 * t + k];
        slot_of[2 * t + k] = slot;
    }
}

__global__ __launch_bounds__(256) void out_init_kernel(
    const int* __restrict__ tk_idx, const float* __restrict__ tk_w,
    const float* __restrict__ b2, float* __restrict__ out)
{
    int t = blockIdx.x;
    int dq = threadIdx.x * 4;
    int e0 = tk_idx[2 * t], e1 = tk_idx[2 * t + 1];
    float w0 = tk_w[2 * t], w1 = tk_w[2 * t + 1];
    f32x4 a = *(const f32x4*)(b2 + (size_t)e0 * EMB + dq);
    f32x4 b = *(const f32x4*)(b2 + (size_t)e1 * EMB + dq);
    f32x4 r;
#pragma unroll
    for (int q = 0; q < 4; q++) r[q] = w0 * a[q] + w1 * b[q];
    *(f32x4*)(out + (size_t)t * EMB + dq) = r;
}

// ---------------- combine: out[t] = w0*(y[s0]+b2[e0]) + w1*(y[s1]+b2[e1]) ----------------
__global__ __launch_bounds__(256) void combine_kernel(
    const float* __restrict__ y, const int* __restrict__ slot_of,
    const int* __restrict__ tk_idx, const float* __restrict__ tk_w,
    const float* __restrict__ b2, float* __restrict__ out)
{
    int t = blockIdx.x;
    int dq = threadIdx.x * 4;
    int s0 = slot_of[2 * t], s1 = slot_of[2 * t + 1];
    int e0 = tk_idx[2 * t], e1 = tk_idx[2 * t + 1];
    float w0 = tk_w[2 * t], w1 = tk_w[2 * t + 1];
    f32x4 ya = *(const f32x4*)(y + (size_t)s0 * EMB + dq);
    f32x4 yb = *(const f32x4*)(y + (size_t)s1 * EMB + dq);
    f32x4 ba = *(const f32x4*)(b2 + (size_t)e0 * EMB + dq);
    f32x4 bb = *(const f32x4*)(b2 + (size_t)e1 * EMB + dq);
    f32x4 r;
#pragma unroll
    for (int q = 0; q < 4; q++) r[q] = w0 * (ya[q] + ba[q]) + w1 * (yb[q] + bb[q]);
    *(f32x4*)(out + (size_t)t * EMB + dq) = r;
}

// ---------------- converts ----------------
__global__ __launch_bounds__(256) void cvt_x_kernel(const float* __restrict__ x, __bf16* __restrict__ xb)
{
    size_t i = ((size_t)blockIdx.x * 256 + threadIdx.x) * 8;
    f32x4 a = *(const f32x4*)(x + i);
    f32x4 b = *(const f32x4*)(x + i + 4);
    bf16x8 o;
#pragma unroll
    for (int q = 0; q < 4; q++) { o[q] = (__bf16)a[q]; o[q + 4] = (__bf16)b[q]; }
    *(bf16x8*)(xb + i) = o;
}

// in [R][C] fp32 per expert -> out [C][R] bf16 per expert. grid (R/64, C/64, NE)
__global__ __launch_bounds__(256) void transpose_cvt_kernel(
    const float* __restrict__ in, __bf16* __restrict__ outb, int R, int C)
{
    int e = blockIdx.z;
    const float* src = in + (size_t)e * R * C;
    __bf16* dst = outb + (size_t)e * R * C;
    __shared__ __bf16 Ls[64 * 72];
    int t = threadIdx.x;
    int r0 = blockIdx.x * 64, c0 = blockIdx.y * 64;
    int ri = t >> 4, cj = (t & 15) * 4;
#pragma unroll
    for (int p = 0; p < 4; p++) {
        int r = ri + p * 16;
        f32x4 v = *(const f32x4*)(src + (size_t)(r0 + r) * C + c0 + cj);
#pragma unroll
        for (int q = 0; q < 4; q++) Ls[(cj + q) * 72 + r] = (__bf16)v[q];
    }
    __syncthreads();
    int c = t >> 2, rq = (t & 3) * 16;
    bf16x8 a = *(bf16x8*)&Ls[c * 72 + rq];
    bf16x8 b = *(bf16x8*)&Ls[c * 72 + rq + 8];
    *(bf16x8*)(dst + (size_t)(c0 + c) * R + r0 + rq) = a;
    *(bf16x8*)(dst + (size_t)(c0 + c) * R + r0 + rq + 8) = b;
}

// ============================================================================
// FAST grouped GEMMs: 128x128 tile, BK=32, global_load_lds(16B) into linear
// LDS with XOR chunk-swizzle (slot = c ^ ((row>>1)&3)) applied on the global
// SOURCE (staging) and on the ds_read side (fragments). 2-phase prefetch:
// issue next K-tile loads, compute current, one barrier per K-step.
// ============================================================================

// h = gelu(xb[tok] @ W1T[e]^T + b1[e]); grid = 8*17*32 flat, XCD-chunk swizzled
__global__ __launch_bounds__(256, 2) void gemm1_fast(
    const __bf16* __restrict__ xb, const __bf16* __restrict__ W1T,
    const float* __restrict__ b1, const __bf16* __restrict__ zp,
    const int* __restrict__ token_id, const int* __restrict__ tile_e,
    const int* __restrict__ tile_rb, const int* __restrict__ ntiles,
    __bf16* __restrict__ h)
{
    int flat = blockIdx.x;
    int c8 = flat & 7, r = flat >> 3;
    int mt = c8 * 17 + (r >> 5);
    int nb = r & 31;
    if (mt >= *ntiles) return;
    int e = tile_e[mt], rb = tile_rb[mt];
    int n0 = nb * 128;

    __shared__ __bf16 As[2][4096];
    __shared__ __bf16 Bs[2][4096];

    int tid = threadIdx.x, lane = tid & 63, wave = tid >> 6;
    int wr = wave >> 1, wc = wave & 1;

    int row0 = tid >> 2;
    int srcoff = (((tid & 3) ^ ((tid >> 3) & 3)) << 3);

    int tok0 = token_id[rb + row0];
    int tok1 = token_id[rb + 64 + row0];
    const __bf16* a0 = (tok0 >= 0 ? xb + (size_t)tok0 * EMB : zp) + srcoff;
    const __bf16* a1 = (tok1 >= 0 ? xb + (size_t)tok1 * EMB : zp) + srcoff;
    const __bf16* bbase = W1T + (size_t)e * FF * EMB + (size_t)n0 * EMB + srcoff;
    const __bf16* b0 = bbase + (size_t)row0 * EMB;
    const __bf16* b1p = bbase + (size_t)(64 + row0) * EMB;

    int wvoff = wave * 512;

    f32x4 acc[4][4];
#pragma unroll
    for (int i = 0; i < 4; i++)
#pragma unroll
        for (int j = 0; j < 4; j++) acc[i][j] = fzero();

    int cl = lane & 15, cq = lane >> 4;
    int xoff = ((cq ^ ((cl >> 1) & 3)) << 3);

    // prologue: stage k0=0 into buf 0
    gl16(a0, &As[0][wvoff]);
    gl16(a1, &As[0][2048 + wvoff]);
    gl16(b0, &Bs[0][wvoff]);
    gl16(b1p, &Bs[0][2048 + wvoff]);
    __syncthreads();

#pragma unroll 2
    for (int t = 0; t < 32; t++) {
        if (t < 31) {
            int nbuf = (t + 1) & 1, k0 = (t + 1) * 32;
            gl16(a0 + k0, &As[nbuf][wvoff]);
            gl16(a1 + k0, &As[nbuf][2048 + wvoff]);
            gl16(b0 + k0, &Bs[nbuf][wvoff]);
            gl16(b1p + k0, &Bs[nbuf][2048 + wvoff]);
        }
        int cb = t & 1;
        bf16x8 af[4], bv[4];
#pragma unroll
        for (int mi = 0; mi < 4; mi++)
            af[mi] = *(const bf16x8*)&As[cb][(wr * 64 + mi * 16 + cl) * 32 + xoff];
#pragma unroll
        for (int ni = 0; ni < 4; ni++)
            bv[ni] = *(const bf16x8*)&Bs[cb][(wc * 64 + ni * 16 + cl) * 32 + xoff];
#pragma unroll
        for (int mi = 0; mi < 4; mi++)
#pragma unroll
            for (int ni = 0; ni < 4; ni++)
                acc[mi][ni] = __builtin_amdgcn_mfma_f32_16x16x32_bf16(af[mi], bv[ni], acc[mi][ni], 0, 0, 0);
        __syncthreads();
    }

    const float* b1g = b1 + (size_t)e * FF + n0;
    int r0 = (lane >> 4) * 4;
#pragma unroll
    for (int mi = 0; mi < 4; mi++) {
#pragma unroll
        for (int ni = 0; ni < 4; ni++) {
            int col = wc * 64 + ni * 16 + cl;
            float bias = b1g[col];
#pragma unroll
            for (int j = 0; j < 4; j++) {
                int row = wr * 64 + mi * 16 + r0 + j;
                float v = acc[mi][ni][j] + bias;
                v = 0.5f * v * (1.0f + erff(v * 0.70710678118654752f));
                h[(size_t)(rb + row) * FF + n0 + col] = (__bf16)v;
            }
        }
    }
}

// y[slot] = h[slot] @ W2T[e]^T  (no bias, no weight; combine applies them)
__global__ __launch_bounds__(256, 2) void gemm2_fast(
    const __bf16* __restrict__ h, const __bf16* __restrict__ W2T,
    const int* __restrict__ tile_e, const int* __restrict__ tile_rb,
    const int* __restrict__ ntiles, float* __restrict__ y)
{
    int flat = blockIdx.x;
    int c8 = flat & 7, r = flat >> 3;
    int mt = c8 * 17 + (r >> 3);
    int nb = r & 7;
    if (mt >= *ntiles) return;
    int e = tile_e[mt], rb = tile_rb[mt];
    int n0 = nb * 128;

    __shared__ __bf16 As[2][4096];
    __shared__ __bf16 Bs[2][4096];

    int tid = threadIdx.x, lane = tid & 63, wave = tid >> 6;
    int wr = wave >> 1, wc = wave & 1;

    int row0 = tid >> 2;
    int srcoff = (((tid & 3) ^ ((tid >> 3) & 3)) << 3);

    const __bf16* a0 = h + (size_t)(rb + row0) * FF + srcoff;
    const __bf16* a1 = h + (size_t)(rb + 64 + row0) * FF + srcoff;
    const __bf16* bbase = W2T + (size_t)e * EMB * FF + (size_t)n0 * FF + srcoff;
    const __bf16* b0 = bbase + (size_t)row0 * FF;
    const __bf16* b1p = bbase + (size_t)(64 + row0) * FF;

    int wvoff = wave * 512;

    f32x4 acc[4][4];
#pragma unroll
    for (int i = 0; i < 4; i++)
#pragma unroll
        for (int j = 0; j < 4; j++) acc[i][j] = fzero();

    int cl = lane & 15, cq = lane >> 4;
    int xoff = ((cq ^ ((cl >> 1) & 3)) << 3);

    gl16(a0, &As[0][wvoff]);
    gl16(a1, &As[0][2048 + wvoff]);
    gl16(b0, &Bs[0][wvoff]);
    gl16(b1p, &Bs[0][2048 + wvoff]);
    __syncthreads();

#pragma unroll 2
    for (int t = 0; t < 128; t++) {
        if (t < 127) {
            int nbuf = (t + 1) & 1, k0 = (t + 1) * 32;
            gl16(a0 + k0, &As[nbuf][wvoff]);
            gl16(a1 + k0, &As[nbuf][2048 + wvoff]);
            gl16(b0 + k0, &Bs[nbuf][wvoff]);
            gl16(b1p + k0, &Bs[nbuf][2048 + wvoff]);
        }
        int cb = t & 1;
        bf16x8 af[4], bv[4];
#pragma unroll
        for (int mi = 0; mi < 4; mi++)
            af[mi] = *(const bf16x8*)&As[cb][(wr * 64 + mi * 16 + cl) * 32 + xoff];
#pragma unroll
        for (int ni = 0; ni < 4; ni++)
            bv[ni] = *(const bf16x8*)&Bs[cb][(wc * 64 + ni * 16 + cl) * 32 + xoff];
#pragma unroll
        for (int mi = 0; mi < 4; mi++)
#pragma unroll
            for (int ni = 0; ni < 4; ni++)
                acc[mi][ni] = __builtin_amdgcn_mfma_f32_16x16x32_bf16(af[mi], bv[ni], acc[mi][ni], 0, 0, 0);
        __syncthreads();
    }

    int r0 = (lane >> 4) * 4;
#pragma unroll
    for (int mi = 0; mi < 4; mi++) {
#pragma unroll
        for (int ni = 0; ni < 4; ni++) {
            int col = wc * 64 + ni * 16 + cl;
#pragma unroll
            for (int j = 0; j < 4; j++) {
                int row = wr * 64 + mi * 16 + r0 + j;
                y[(size_t)(rb + row) * EMB + n0 + col] = acc[mi][ni][j];
            }
        }
    }
}

// ============================================================================
// SLOW fallback (round-2 verified): reg-staged, fp32 weights, atomics
// ============================================================================
__global__ __launch_bounds__(256) void gemm1_slow(
    const float* __restrict__ x, const float* __restrict__ W1, const float* __restrict__ b1,
    const int* __restrict__ token_id, const int* __restrict__ tile_e, const int* __restrict__ tile_rb,
    const int* __restrict__ ntiles, __bf16* __restrict__ h, int ffc, int chunk)
{
    int mt = blockIdx.x;
    if (mt >= *ntiles) return;
    int e  = tile_e[mt];
    int rb = tile_rb[mt];
    int n0loc = blockIdx.y * 128;

    const float* b1g = b1 + (size_t)e * FF + (size_t)chunk * ffc + n0loc;

    __shared__ __bf16 As[128 * 40];
    __shared__ __bf16 Bs[128 * 40];

    int tid = threadIdx.x, lane = tid & 63, wave = tid >> 6;
    int wr = wave >> 1, wc = wave & 1;

    int arow = tid >> 1;
    int half = tid & 1;
    int tok = token_id[rb + arow];

    f32x4 acc[4][4];
#pragma unroll
    for (int i = 0; i < 4; i++)
#pragma unroll
        for (int j = 0; j < 4; j++) acc[i][j] = fzero();

    int cl = lane & 15;
    int k8 = (lane >> 4) * 8;

    const float* asrc = (tok >= 0) ? (x + (size_t)tok * EMB + half * 16) : (const float*)0;
    const float* Bbase = W1 + (size_t)e * EMB * FF + (size_t)chunk * ffc + n0loc;
    int bk = tid >> 3;
    int nb = (tid & 7) * 16;
    for (int k0 = 0; k0 < EMB; k0 += 32) {
#pragma unroll
        for (int j = 0; j < 2; j++) {
            f32x4 v = asrc ? *(const f32x4*)(asrc + k0 + j * 4) : fzero();
            bf16x4 s;
#pragma unroll
            for (int q = 0; q < 4; q++) s[q] = (__bf16)v[q];
            *(bf16x4*)&As[arow * 40 + half * 16 + j * 4] = s;
            f32x4 v2 = asrc ? *(const f32x4*)(asrc + k0 + 8 + j * 4) : fzero();
            bf16x4 s2;
#pragma unroll
            for (int q = 0; q < 4; q++) s2[q] = (__bf16)v2[q];
            *(bf16x4*)&As[arow * 40 + half * 16 + 8 + j * 4] = s2;
        }
        const float* bs = Bbase + (size_t)(k0 + bk) * FF + nb;
#pragma unroll
        for (int j = 0; j < 4; j++) {
            f32x4 v = *(const f32x4*)(bs + j * 4);
#pragma unroll
            for (int q = 0; q < 4; q++) Bs[(nb + j * 4 + q) * 40 + bk] = (__bf16)v[q];
        }
        __syncthreads();

        bf16x8 af[4], bfr[4];
#pragma unroll
        for (int mi = 0; mi < 4; mi++) af[mi] = *(bf16x8*)&As[(wr * 64 + mi * 16 + cl) * 40 + k8];
#pragma unroll
        for (int ni = 0; ni < 4; ni++) bfr[ni] = *(bf16x8*)&Bs[(wc * 64 + ni * 16 + cl) * 40 + k8];
#pragma unroll
        for (int mi = 0; mi < 4; mi++)
#pragma unroll
            for (int ni = 0; ni < 4; ni++)
                acc[mi][ni] = __builtin_amdgcn_mfma_f32_16x16x32_bf16(af[mi], bfr[ni], acc[mi][ni], 0, 0, 0);
        __syncthreads();
    }

    int r0 = (lane >> 4) * 4;
#pragma unroll
    for (int mi = 0; mi < 4; mi++) {
#pragma unroll
        for (int ni = 0; ni < 4; ni++) {
            int col = wc * 64 + ni * 16 + cl;
            float bias = b1g[col];
#pragma unroll
            for (int j = 0; j < 4; j++) {
                int row = wr * 64 + mi * 16 + r0 + j;
                float v = acc[mi][ni][j] + bias;
                v = 0.5f * v * (1.0f + erff(v * 0.70710678118654752f));
                h[(size_t)(rb + row) * ffc + n0loc + col] = (__bf16)v;
            }
        }
    }
}

__global__ __launch_bounds__(256) void gemm2_slow(
    const __bf16* __restrict__ h, const float* __restrict__ W2,
    const int* __restrict__ token_id, const float* __restrict__ roww,
    const int* __restrict__ tile_e, const int* __restrict__ tile_rb,
    const int* __restrict__ ntiles, float* __restrict__ out, int ffc, int chunk)
{
    int mt = blockIdx.x;
    if (mt >= *ntiles) return;
    int e  = tile_e[mt];
    int rb = tile_rb[mt];
    int n0 = blockIdx.y * 128;

    __shared__ __bf16 As[128 * 40];
    __shared__ __bf16 Bs[128 * 40];

    int tid = threadIdx.x, lane = tid & 63, wave = tid >> 6;
    int wr = wave >> 1, wc = wave & 1;

    int arow = tid >> 1;
    int half = tid & 1;
    const __bf16* hrow = h + (size_t)(rb + arow) * ffc + half * 16;

    f32x4 acc[4][4];
#pragma unroll
    for (int i = 0; i < 4; i++)
#pragma unroll
        for (int j = 0; j < 4; j++) acc[i][j] = fzero();

    int cl = lane & 15;
    int k8 = (lane >> 4) * 8;

    const float* Bbase = W2 + (size_t)e * FF * EMB + (size_t)chunk * ffc * EMB + n0;
    int bk = tid >> 3;
    int nb = (tid & 7) * 16;
    for (int k0 = 0; k0 < ffc; k0 += 32) {
        uint4 v0 = *(const uint4*)(hrow + k0);
        uint4 v1 = *(const uint4*)(hrow + k0 + 8);
        *(uint4*)&As[arow * 40 + half * 16] = v0;
        *(uint4*)&As[arow * 40 + half * 16 + 8] = v1;
        const float* bs = Bbase + (size_t)(k0 + bk) * EMB + nb;
#pragma unroll
        for (int j = 0; j < 4; j++) {
            f32x4 v = *(const f32x4*)(bs + j * 4);
#pragma unroll
            for (int q = 0; q < 4; q++) Bs[(nb + j * 4 + q) * 40 + bk] = (__bf16)v[q];
        }
        __syncthreads();

        bf16x8 af[4], bfr[4];
#pragma unroll
        for (int mi = 0; mi < 4; mi++) af[mi] = *(bf16x8*)&As[(wr * 64 + mi * 16 + cl) * 40 + k8];
#pragma unroll
        for (int ni = 0; ni < 4; ni++) bfr[ni] = *(bf16x8*)&Bs[(wc * 64 + ni * 16 + cl) * 40 + k8];
#pragma unroll
        for (int mi = 0; mi < 4; mi++)
#pragma unroll
            for (int ni = 0; ni < 4; ni++)
                acc[mi][ni] = __builtin_amdgcn_mfma_f32_16x16x32_bf16(af[mi], bfr[ni], acc[mi][ni], 0, 0, 0);
        __syncthreads();
    }

    int r0 = (lane >> 4) * 4;
#pragma unroll
    for (int mi = 0; mi < 4; mi++) {
#pragma unroll
        for (int ni = 0; ni < 4; ni++) {
            int col = wc * 64 + ni * 16 + cl;
#pragma unroll
            for (int j = 0; j < 4; j++) {
                int row = wr * 64 + mi * 16 + r0 + j;
                int gr = rb + row;
                int tok = token_id[gr];
                if (tok >= 0)
                    atomicAdd(out + (size_t)tok * EMB + n0 + col, roww[gr] * acc[mi][ni][j]);
            }
        }
    }
}

extern "C" void kernel_launch(void* const* d_in, const int* in_sizes, int n_in,
                              void* d_out, int out_size, void* d_ws, size_t ws_size,
                              hipStream_t stream)
{
    const float* x   = (const float*)d_in[0];
    const float* gW  = (const float*)d_in[1];
    const float* gb  = (const float*)d_in[2];
    const float* W1  = (const float*)d_in[3];
    const float* b1  = (const float*)d_in[4];
    const float* W2  = (const float*)d_in[5];
    const float* b2  = (const float*)d_in[6];
    float* out = (float*)d_out;

    char* ws = (char*)d_ws;
    int*   counts  = (int*)(ws + WS_COUNTS);
    int*   cursors = (int*)(ws + WS_CURSORS);
    float* ssum    = (float*)(ws + WS_SSUM);
    int*   ntiles  = (int*)(ws + WS_NTILES);
    int*   base    = (int*)(ws + WS_BASE);
    int*   tile_e  = (int*)(ws + WS_TILE_E);
    int*   tile_rb = (int*)(ws + WS_TILE_RB);
    int*   tk_idx  = (int*)(ws + WS_TKIDX);
    float* tk_w    = (float*)(ws + WS_TKW);
    int*   token_id= (int*)(ws + WS_TOKID);
    float* roww    = (float*)(ws + WS_ROWW);
    int*   slot_of = (int*)(ws + WS_SLOT);
    __bf16* zp     = (__bf16*)(ws + WS_ZP);

    bool fast = ws_size >= WS_BIG2 + SZ_W1T + SZ_XB + SZ_W2T + SZ_H;

    __bf16* W1T = (__bf16*)(ws + WS_BIG2);
    __bf16* xb  = (__bf16*)(ws + WS_BIG2 + SZ_W1T);
    __bf16* W2T = (__bf16*)(ws + WS_BIG2 + SZ_W1T + SZ_XB);
    __bf16* hbuf= (__bf16*)(ws + WS_BIG2 + SZ_W1T + SZ_XB + SZ_W2T);
    float*  ybuf= (float*)(ws + WS_BIG2);   // aliases W1T+xb (dead after gemm1)

    hipMemsetAsync(ws + WS_COUNTS, 0, 2080, stream);
    hipMemsetAsync(ws + WS_TOKID, 0xFF, (size_t)MAXROWS * 4, stream);

    if (fast) {
        hipMemsetAsync(ws + WS_ZP, 0, 2048, stream);
        cvt_x_kernel<<<TTOK * EMB / 2048, 256, 0, stream>>>(x, xb);
        transpose_cvt_kernel<<<dim3(EMB / 64, FF / 64, NE), 256, 0, stream>>>(W1, W1T, EMB, FF);
        transpose_cvt_kernel<<<dim3(FF / 64, EMB / 64, NE), 256, 0, stream>>>(W2, W2T, FF, EMB);
    }

    gate_kernel<<<TTOK / 4, 256, 0, stream>>>(x, gW, gb, counts, ssum, tk_idx, tk_w);
    route_build_kernel<<<1, 64, 0, stream>>>(counts, ssum, ntiles, base, tile_e, tile_rb,
                                             out + (size_t)TTOK * EMB);
    scatter_kernel<<<TTOK / 256, 256, 0, stream>>>(tk_idx, tk_w, base, cursors, token_id, roww, slot_of);

    if (fast) {
        gemm1_fast<<<8 * 17 * 32, 256, 0, stream>>>(
            xb, W1T, b1, zp, token_id, tile_e, tile_rb, ntiles, hbuf);
        gemm2_fast<<<8 * 17 * 8, 256, 0, stream>>>(
            hbuf, W2T, tile_e, tile_rb, ntiles, ybuf);
        combine_kernel<<<TTOK, 256, 0, stream>>>(ybuf, slot_of, tk_idx, tk_w, b2, out);
    } else {
        int ffc = 512;
        for (int f = 4096; f >= 512; f >>= 1)
            if (ws_size >= WS_BIG2 + (size_t)MAXROWS * f * 2) { ffc = f; break; }
        __bf16* hs = (__bf16*)(ws + WS_BIG2);
        out_init_kernel<<<TTOK, 256, 0, stream>>>(tk_idx, tk_w, b2, out);
        int nchunks = FF / ffc;
        for (int c = 0; c < nchunks; c++) {
            gemm1_slow<<<dim3(MAXTILES, ffc / 128), 256, 0, stream>>>(
                x, W1, b1, token_id, tile_e, tile_rb, ntiles, hs, ffc, c);
            gemm2_slow<<<dim3(MAXTILES, EMB / 128), 256, 0, stream>>>(
                hs, W2, token_id, roww, tile_e, tile_rb, ntiles, out, ffc, c);
        }
    }
}